// Round 5
// baseline (308.186 us; speedup 1.0000x reference)
//
#include <hip/hip_runtime.h>
#include <hip/hip_cooperative_groups.h>
#include <hip/hip_bf16.h>

namespace cg = cooperative_groups;

#define BD 4
#define SD 2048
#define DD 512
#define VD 32000
#define NTOK (BD * SD)
#define EPS_L2 1e-12f
#define NBLK 768
#define NTHR 256
#define NWAVE ((NBLK * NTHR) / 64)  // 3072

// ws layout: [ head V int ][ next NTOK int ][ pgw NTOK f32 ][ lossPart 256 f32 ]
#define WS_NEXT VD
#define WS_PGW (VD + NTOK)
#define WS_LOSSP (VD + 2 * NTOK)

__global__ void __launch_bounds__(NTHR, 4)
fused_kernel(const float* __restrict__ x, const float* __restrict__ p,
             const int* __restrict__ gold, const int* __restrict__ mask,
             const float* __restrict__ cache, float* __restrict__ out,
             int* __restrict__ head, int* __restrict__ next,
             float* __restrict__ pgw, float* __restrict__ lossPart) {
    cg::grid_group grid = cg::this_grid();
    int gtid = blockIdx.x * NTHR + threadIdx.x;
    int lane = threadIdx.x & 63;

    // P0: init
    for (int v = gtid; v < VD; v += NBLK * NTHR) head[v] = -1;
    if (gtid < 256) lossPart[gtid] = 0.f;
    grid.sync();

    // P1: build per-vocab token lists; stash p_gold with pad folded in sign.
    if (gtid < NTOK) {
        int g = gold[gtid];
        next[gtid] = atomicExch(&head[g], gtid);
        float pg = p[(size_t)gtid * VD + g];
        pgw[gtid] = mask[gtid] ? -1.f : pg;  // p >= 0; sign marks pad
    }
    __threadfence();
    grid.sync();

    // P2: one wave per vocab row, grid-strided.
    int wave = gtid >> 6;
    float lossAcc = 0.f;
    for (int row = wave; row < VD; row += NWAVE) {
        const float4* cr = (const float4*)cache + (size_t)row * (DD / 4);
        float4 ca = cr[lane], cb = cr[64 + lane];
        float* o = out + 1 + (size_t)row * DD;
        int b = lane * 4;
        int t = head[row];

        if (t < 0) {  // untouched row: passthrough copy
            o[b + 0] = ca.x; o[b + 1] = ca.y; o[b + 2] = ca.z; o[b + 3] = ca.w;
            o[256 + b + 0] = cb.x; o[256 + b + 1] = cb.y;
            o[256 + b + 2] = cb.z; o[256 + b + 3] = cb.w;
            continue;
        }

        float sc = ca.x * ca.x + ca.y * ca.y + ca.z * ca.z + ca.w * ca.w
                 + cb.x * cb.x + cb.y * cb.y + cb.z * cb.z + cb.w * cb.w;
        #pragma unroll
        for (int off = 32; off; off >>= 1) sc += __shfl_xor(sc, off, 64);
        float rnc = 1.0f / fmaxf(sqrtf(sc), EPS_L2);

        float4 aa = {0.f, 0.f, 0.f, 0.f}, ab = {0.f, 0.f, 0.f, 0.f};
        int cnt = 0;
        while (t >= 0) {
            int tn = next[t];
            float w = pgw[t];  // broadcast; < 0 means padded
            const float4* xr = (const float4*)x + (size_t)t * (DD / 4);
            float4 xa = xr[lane], xb = xr[64 + lane];

            float dot = xa.x * ca.x + xa.y * ca.y + xa.z * ca.z + xa.w * ca.w
                      + xb.x * cb.x + xb.y * cb.y + xb.z * cb.z + xb.w * cb.w;
            float sx = xa.x * xa.x + xa.y * xa.y + xa.z * xa.z + xa.w * xa.w
                     + xb.x * xb.x + xb.y * xb.y + xb.z * xb.z + xb.w * xb.w;
            #pragma unroll
            for (int off = 32; off; off >>= 1) {
                dot += __shfl_xor(dot, off, 64);
                sx += __shfl_xor(sx, off, 64);
            }
            cnt++;  // counts include padded tokens (ref semantics)
            if (w >= 0.f) {
                float rnx = 1.0f / fmaxf(sqrtf(sx), EPS_L2);
                lossAcc += 2.f - 2.f * dot * rnx * rnc;
                aa.x += w * xa.x; aa.y += w * xa.y;
                aa.z += w * xa.z; aa.w += w * xa.w;
                ab.x += w * xb.x; ab.y += w * xb.y;
                ab.z += w * xb.z; ab.w += w * xb.w;
            }
            t = tn;
        }

        float m = 0.1f / (float)cnt;
        o[b + 0] = 0.9f * ca.x + m * aa.x;
        o[b + 1] = 0.9f * ca.y + m * aa.y;
        o[b + 2] = 0.9f * ca.z + m * aa.z;
        o[b + 3] = 0.9f * ca.w + m * aa.w;
        o[256 + b + 0] = 0.9f * cb.x + m * ab.x;
        o[256 + b + 1] = 0.9f * cb.y + m * ab.y;
        o[256 + b + 2] = 0.9f * cb.z + m * ab.z;
        o[256 + b + 3] = 0.9f * cb.w + m * ab.w;
    }
    if (lane == 0 && lossAcc != 0.f) atomicAdd(&lossPart[wave & 255], lossAcc);
    grid.sync();

    // P3: block 0 reduces loss partials.
    if (blockIdx.x == 0) {
        __shared__ float sm[4];
        float a = lossPart[threadIdx.x];
        #pragma unroll
        for (int off = 32; off; off >>= 1) a += __shfl_xor(a, off, 64);
        if ((threadIdx.x & 63) == 0) sm[threadIdx.x >> 6] = a;
        __syncthreads();
        if (threadIdx.x == 0) out[0] = sm[0] + sm[1] + sm[2] + sm[3];
    }
}

extern "C" void kernel_launch(void* const* d_in, const int* in_sizes, int n_in,
                              void* d_out, int out_size, void* d_ws, size_t ws_size,
                              hipStream_t stream) {
    const float* x = (const float*)d_in[0];
    const float* p = (const float*)d_in[1];
    const int* gold = (const int*)d_in[2];
    const int* mask = (const int*)d_in[3];
    const float* cache = (const float*)d_in[4];
    float* out = (float*)d_out;
    int* head = (int*)d_ws;
    int* next = head + WS_NEXT;
    float* pgw = (float*)d_ws + WS_PGW;
    float* lossPart = (float*)d_ws + WS_LOSSP;

    void* args[] = {&x, &p, &gold, &mask, &cache, &out,
                    &head, &next, &pgw, &lossPart};
    hipLaunchCooperativeKernel(reinterpret_cast<void*>(fused_kernel),
                               dim3(NBLK), dim3(NTHR), args, 0, stream);
}